// Round 5
// baseline (444.463 us; speedup 1.0000x reference)
//
#include <hip/hip_runtime.h>

#define K_TOP 5000
#define NBIN 2048
#define NB_BUCKET 4096
#define TARGET_SAMPLED 94u   // ~12000 true candidates at 1/128 sampling

typedef float vfloat4 __attribute__((ext_vector_type(4)));

// ---- order-preserving float<->key mapping -------------------------------
__device__ __forceinline__ unsigned f2key(float f) {
    unsigned u = __float_as_uint(f);
    return (u & 0x80000000u) ? ~u : (u | 0x80000000u);
}
__device__ __forceinline__ float key2f(unsigned k) {
    unsigned u = (k & 0x80000000u) ? (k ^ 0x80000000u) : ~k;
    return __uint_as_float(u);
}

// ---- sampled histogram: 64 consecutive float4 of every 8192 (1/128) -----
__global__ __launch_bounds__(256) void k_sample(const float4* __restrict__ x4, long n4,
                                                unsigned* __restrict__ hist) {
    __shared__ unsigned lh[NBIN];
    for (int i = threadIdx.x; i < NBIN; i += 256) lh[i] = 0;
    __syncthreads();
    int wave = threadIdx.x >> 6;
    int lane = threadIdx.x & 63;
    long gw = (long)blockIdx.x * 4 + wave;
    long totW = (long)gridDim.x * 4;
    long nChunk = (n4 + 8191) / 8192;
    for (long c = gw; c < nChunk; c += totW) {
        long i = c * 8192 + lane;
        if (i < n4) {
            float4 v = x4[i];
            atomicAdd(&lh[f2key(v.x) >> 21], 1u);
            atomicAdd(&lh[f2key(v.y) >> 21], 1u);
            atomicAdd(&lh[f2key(v.z) >> 21], 1u);
            atomicAdd(&lh[f2key(v.w) >> 21], 1u);
        }
    }
    __syncthreads();
    for (int i = threadIdx.x; i < NBIN; i += 256) {
        unsigned c = lh[i];
        if (c) atomicAdd(&hist[i], c);
    }
}

// ---- pick conservative threshold L from sampled histogram ---------------
// ctrl: [0]=candCount [1]=L
__global__ __launch_bounds__(256) void k_findbin(const unsigned* __restrict__ hist,
                                                 unsigned* __restrict__ ctrl) {
    __shared__ unsigned lh[NBIN];
    __shared__ unsigned gs[64];
    for (int i = threadIdx.x; i < NBIN; i += 256) lh[i] = hist[i];
    __syncthreads();
    int t = threadIdx.x;
    if (t < 64) {
        unsigned s = 0;
        for (int j = 0; j < 32; j++) s += lh[t * 32 + j];
        gs[t] = s;
    }
    __syncthreads();
    if (t == 0) {
        unsigned cum = 0;
        int g = 63;
        for (; g > 0; g--) { if (cum + gs[g] >= TARGET_SAMPLED) break; cum += gs[g]; }
        int b = g * 32 + 31;
        for (; b > g * 32; b--) { if (cum + lh[b] >= TARGET_SAMPLED) break; cum += lh[b]; }
        ctrl[1] = ((unsigned)b) << 21;
    }
}

// ---- full pass: persistent grid, 4-deep NT loads, ballot fast path ------
__global__ __launch_bounds__(256, 8) void k_compact(const vfloat4* __restrict__ x4, long n4,
                                                    long n, const float* __restrict__ x,
                                                    unsigned* __restrict__ ctrl,
                                                    unsigned* __restrict__ candKey,
                                                    unsigned* __restrict__ candIdx,
                                                    unsigned capC) {
    unsigned L = ctrl[1];
    float Lf = key2f(L);
    const vfloat4 neg = {-1e38f, -1e38f, -1e38f, -1e38f};
    long tiles = (n4 + 1023) >> 10;
    for (long tile = blockIdx.x; tile < tiles; tile += gridDim.x) {
        long b0 = (tile << 10) + threadIdx.x;
        long b1 = b0 + 256, b2 = b0 + 512, b3 = b0 + 768;
        bool in0 = b0 < n4, in1 = b1 < n4, in2 = b2 < n4, in3 = b3 < n4;
        vfloat4 v0 = neg, v1 = neg, v2 = neg, v3 = neg;
        if (in0) v0 = __builtin_nontemporal_load(x4 + b0);
        if (in1) v1 = __builtin_nontemporal_load(x4 + b1);
        if (in2) v2 = __builtin_nontemporal_load(x4 + b2);
        if (in3) v3 = __builtin_nontemporal_load(x4 + b3);
        float m01 = fmaxf(fmaxf(fmaxf(v0.x, v0.y), fmaxf(v0.z, v0.w)),
                          fmaxf(fmaxf(v1.x, v1.y), fmaxf(v1.z, v1.w)));
        float m23 = fmaxf(fmaxf(fmaxf(v2.x, v2.y), fmaxf(v2.z, v2.w)),
                          fmaxf(fmaxf(v3.x, v3.y), fmaxf(v3.z, v3.w)));
        if (__any(fmaxf(m01, m23) >= Lf)) {
#define PROC(vv, inb, ii)                                                        \
            if (inb) {                                                           \
                unsigned bb = (unsigned)((ii) * 4);                              \
                _Pragma("unroll")                                                \
                for (int c = 0; c < 4; c++) {                                    \
                    float f = (vv)[c];                                           \
                    if (f >= Lf) {                                               \
                        unsigned p = atomicAdd(&ctrl[0], 1u);                    \
                        if (p < capC) { candKey[p] = f2key(f);                   \
                                        candIdx[p] = bb + (unsigned)c; }         \
                    }                                                            \
                }                                                                \
            }
            PROC(v0, in0, b0)
            PROC(v1, in1, b1)
            PROC(v2, in2, b2)
            PROC(v3, in3, b3)
#undef PROC
        }
    }
    // tail (n % 4), block 0 only
    if (blockIdx.x == 0 && threadIdx.x < (int)(n & 3)) {
        float f = x[n4 * 4 + threadIdx.x];
        if (f >= Lf) {
            unsigned p = atomicAdd(&ctrl[0], 1u);
            if (p < capC) { candKey[p] = f2key(f); candIdx[p] = (unsigned)(n4 * 4 + threadIdx.x); }
        }
    }
}

// ---- fused finalize: exact T + tie-break + bucket sort + emit -----------
__global__ __launch_bounds__(1024) void k_final(const unsigned* __restrict__ candKey,
                                                const unsigned* __restrict__ candIdx,
                                                unsigned* __restrict__ ctrl, unsigned capC,
                                                unsigned* __restrict__ selKey,
                                                unsigned* __restrict__ selIdx,
                                                unsigned* __restrict__ selKeyS,
                                                unsigned* __restrict__ selIdxS,
                                                float* __restrict__ out, long n, int bshift) {
    __shared__ unsigned h[NB_BUCKET * 2];   // 32 KB
    __shared__ unsigned part[1024];
    __shared__ unsigned part2[32];
    __shared__ unsigned res[2];
    __shared__ unsigned sScalar;
    const int t = threadIdx.x;
    unsigned Nc = ctrl[0]; if (Nc > capC) Nc = capC;
    unsigned L = ctrl[1];

    // --- max key ---
    unsigned mk = 0;
    for (unsigned i = t; i < Nc; i += 1024) { unsigned k = candKey[i]; if (k > mk) mk = k; }
    part[t] = mk;
    __syncthreads();
    if (t < 32) { unsigned m = 0; for (int j = 0; j < 32; j++) { unsigned v = part[t * 32 + j]; if (v > m) m = v; } part2[t] = m; }
    __syncthreads();
    if (t == 0) { unsigned m = 0; for (int j = 0; j < 32; j++) if (part2[j] > m) m = part2[j]; sScalar = m; }
    __syncthreads();
    unsigned maxK = sScalar;

    // --- iterative radix-select: K_TOP-th from top ---
    unsigned lo = L, target = K_TOP;
    unsigned range = maxK - lo;
    int shift = 0;
    while ((range >> shift) >= NBIN) shift++;
    for (;;) {
        int nb = (int)(range >> shift) + 1;
        for (int i = t; i < nb; i += 1024) h[i] = 0;
        __syncthreads();
        for (unsigned i = t; i < Nc; i += 1024) {
            unsigned d = candKey[i] - lo;
            if (d <= range) atomicAdd(&h[d >> shift], 1u);
        }
        __syncthreads();
        int ng = (nb + 31) >> 5;
        if (t < ng) {
            unsigned s = 0; int b0 = t * 32, e = b0 + 32; if (e > nb) e = nb;
            for (int j = b0; j < e; j++) s += h[j];
            part[t] = s;
        }
        __syncthreads();
        if (t == 0) {
            unsigned cum = 0; int g = ng - 1;
            for (; g > 0; g--) { if (cum + part[g] >= target) break; cum += part[g]; }
            int hi2 = g * 32 + 31; if (hi2 > nb - 1) hi2 = nb - 1;
            int b = hi2;
            for (; b > g * 32; b--) { if (cum + h[b] >= target) break; cum += h[b]; }
            res[0] = (unsigned)b; res[1] = target - cum;
        }
        __syncthreads();
        lo += res[0] << shift; target = res[1];
        if (shift == 0) break;
        range = (1u << shift) - 1;
        shift = (shift > 11) ? shift - 11 : 0;
    }
    unsigned T = lo, R = target;

    // --- count equal keys ---
    if (t == 0) sScalar = 0;
    __syncthreads();
    for (unsigned i = t; i < Nc; i += 1024)
        if (candKey[i] == T) atomicAdd(&sScalar, 1u);
    __syncthreads();
    unsigned cntEq = sScalar;
    unsigned idxCut = 0xFFFFFFFFu;
    if (cntEq != R) {  // uniform branch
        unsigned lo2 = 0, tgt = R;
        unsigned range2 = (unsigned)(n - 1);
        int sh = 0;
        while ((range2 >> sh) >= NBIN) sh++;
        for (;;) {
            int nb = (int)(range2 >> sh) + 1;
            for (int i = t; i < nb; i += 1024) h[i] = 0;
            __syncthreads();
            for (unsigned i = t; i < Nc; i += 1024)
                if (candKey[i] == T) {
                    unsigned d = candIdx[i] - lo2;
                    if (d <= range2) atomicAdd(&h[d >> sh], 1u);
                }
            __syncthreads();
            int ng = (nb + 31) >> 5;
            if (t < ng) {
                unsigned s = 0; int b0 = t * 32, e = b0 + 32; if (e > nb) e = nb;
                for (int j = b0; j < e; j++) s += h[j];
                part[t] = s;
            }
            __syncthreads();
            if (t == 0) {
                unsigned cum = 0; int g = 0;
                for (; g < ng - 1; g++) { if (cum + part[g] >= tgt) break; cum += part[g]; }
                int b = g * 32; int hi2 = g * 32 + 31; if (hi2 > nb - 1) hi2 = nb - 1;
                for (; b < hi2; b++) { if (cum + h[b] >= tgt) break; cum += h[b]; }
                res[0] = (unsigned)b; res[1] = tgt - cum;
            }
            __syncthreads();
            lo2 += res[0] << sh; tgt = res[1];
            if (sh == 0) break;
            range2 = (1u << sh) - 1;
            sh = (sh > 11) ? sh - 11 : 0;
        }
        idxCut = lo2;
    }
    __syncthreads();

    // --- select exactly K, count buckets ---
    for (int i = t; i < NB_BUCKET; i += 1024) h[i] = 0;
    if (t == 0) sScalar = 0;
    __syncthreads();
    for (unsigned i = t; i < Nc; i += 1024) {
        unsigned k = candKey[i]; unsigned id = candIdx[i];
        if (k > T || (k == T && id <= idxCut)) {
            unsigned p = atomicAdd(&sScalar, 1u);
            if (p < K_TOP) {
                selKey[p] = k; selIdx[p] = id;
                atomicAdd(&h[id >> bshift], 1u);
            }
        }
    }
    __syncthreads();
    unsigned nSel = sScalar; if (nSel > K_TOP) nSel = K_TOP;

    // --- exclusive scan of bucket counts ---
    unsigned* bc = h;
    unsigned* bs = h + NB_BUCKET;
    { unsigned s = 0; for (int j = 0; j < 4; j++) s += bc[t * 4 + j]; part[t] = s; }
    __syncthreads();
    if (t < 32) { unsigned s = 0; for (int j = 0; j < 32; j++) s += part[t * 32 + j]; part2[t] = s; }
    __syncthreads();
    if (t == 0) { unsigned run = 0; for (int j = 0; j < 32; j++) { unsigned v = part2[j]; part2[j] = run; run += v; } }
    __syncthreads();
    if (t < 32) { unsigned run = part2[t]; for (int j = 0; j < 32; j++) { int id2 = t * 32 + j; unsigned v = part[id2]; part[id2] = run; run += v; } }
    __syncthreads();
    { unsigned run = part[t]; for (int j = 0; j < 4; j++) { bs[t * 4 + j] = run; run += bc[t * 4 + j]; } }
    __syncthreads();

    // --- scatter into bucket order (bs becomes cursor) ---
    for (unsigned g = t; g < nSel; g += 1024) {
        unsigned id = selIdx[g];
        unsigned b = id >> bshift;
        unsigned p = atomicAdd(&bs[b], 1u);
        if (p < K_TOP) { selKeyS[p] = selKey[g]; selIdxS[p] = id; }
    }
    __syncthreads();

    // --- per-bucket insertion sort by idx + emit ---
    for (int j = 0; j < 4; j++) {
        int b = t * 4 + j;
        unsigned cnt = bc[b];
        if (!cnt) continue;
        unsigned s = bs[b] - cnt;
        for (unsigned i = 0; i < cnt; i++) {
            unsigned mi = i, mv = selIdxS[s + i];
            for (unsigned q = i + 1; q < cnt; q++) {
                unsigned v = selIdxS[s + q];
                if (v < mv) { mv = v; mi = q; }
            }
            if (mi != i) {
                unsigned ti = selIdxS[s + i]; selIdxS[s + i] = selIdxS[s + mi]; selIdxS[s + mi] = ti;
                unsigned tk = selKeyS[s + i]; selKeyS[s + i] = selKeyS[s + mi]; selKeyS[s + mi] = tk;
            }
            out[s + i] = key2f(selKeyS[s + i]);
        }
    }
}

// ---- host launch --------------------------------------------------------
// ws words: hist[0..2047], ctrl[2048..2055], selKey[2056..7055], selIdx[7056..12055],
//           selKeyS[12056..17055], selIdxS[17056..22055], cand arrays from 24576.
extern "C" void kernel_launch(void* const* d_in, const int* in_sizes, int n_in,
                              void* d_out, int out_size, void* d_ws, size_t ws_size,
                              hipStream_t stream) {
    const float* x = (const float*)d_in[0];
    long n = in_sizes[0];
    float* out = (float*)d_out;
    unsigned* w = (unsigned*)d_ws;

    unsigned* hist    = w;
    unsigned* ctrl    = w + 2048;
    unsigned* selKey  = w + 2056;
    unsigned* selIdx  = w + 7056;
    unsigned* selKeyS = w + 12056;
    unsigned* selIdxS = w + 17056;
    const size_t CAND_BASE = 24576;
    size_t words = ws_size / 4;
    unsigned capC = 0;
    if (words > CAND_BASE + 64) {
        size_t c = (words - CAND_BASE) / 2;
        if (c > (size_t)(4u << 20)) c = (size_t)(4u << 20);
        capC = (unsigned)c;
    }
    unsigned* candKey = w + CAND_BASE;
    unsigned* candIdx = candKey + capC;

    int bshift = 0;
    while (((n - 1) >> bshift) >= NB_BUCKET) bshift++;

    (void)hipMemsetAsync(d_ws, 0, 2056u * 4u + 32u, stream);

    long n4 = n / 4;
    k_sample<<<256, 256, 0, stream>>>((const float4*)x, n4, hist);
    k_findbin<<<1, 256, 0, stream>>>(hist, ctrl);
    k_compact<<<4096, 256, 0, stream>>>((const vfloat4*)x, n4, n, x, ctrl,
                                        candKey, candIdx, capC);
    k_final<<<1, 1024, 0, stream>>>(candKey, candIdx, ctrl, capC,
                                    selKey, selIdx, selKeyS, selIdxS, out, n, bshift);
}

// Round 6
// 422.710 us; speedup vs baseline: 1.0515x; 1.0515x over previous
//
#include <hip/hip_runtime.h>

#define K_TOP 5000
#define NBIN 2048
#define NB_BUCKET 4096
#define TARGET_SAMPLED 94u   // ~12000 true candidates at 1/128 sampling

typedef float vfloat4 __attribute__((ext_vector_type(4)));

// ---- order-preserving float<->key mapping -------------------------------
__device__ __forceinline__ unsigned f2key(float f) {
    unsigned u = __float_as_uint(f);
    return (u & 0x80000000u) ? ~u : (u | 0x80000000u);
}
__device__ __forceinline__ float key2f(unsigned k) {
    unsigned u = (k & 0x80000000u) ? (k ^ 0x80000000u) : ~k;
    return __uint_as_float(u);
}

// ---- sampled histogram: 64 consecutive float4 of every 8192 (1/128) -----
__global__ __launch_bounds__(256) void k_sample(const float4* __restrict__ x4, long n4,
                                                unsigned* __restrict__ hist) {
    __shared__ unsigned lh[NBIN];
    for (int i = threadIdx.x; i < NBIN; i += 256) lh[i] = 0;
    __syncthreads();
    int wave = threadIdx.x >> 6;
    int lane = threadIdx.x & 63;
    long gw = (long)blockIdx.x * 4 + wave;
    long totW = (long)gridDim.x * 4;
    long nChunk = (n4 + 8191) / 8192;
    for (long c = gw; c < nChunk; c += totW) {
        long i = c * 8192 + lane;
        if (i < n4) {
            float4 v = x4[i];
            atomicAdd(&lh[f2key(v.x) >> 21], 1u);
            atomicAdd(&lh[f2key(v.y) >> 21], 1u);
            atomicAdd(&lh[f2key(v.z) >> 21], 1u);
            atomicAdd(&lh[f2key(v.w) >> 21], 1u);
        }
    }
    __syncthreads();
    for (int i = threadIdx.x; i < NBIN; i += 256) {
        unsigned c = lh[i];
        if (c) atomicAdd(&hist[i], c);
    }
}

// ---- pick conservative threshold L from sampled histogram ---------------
// ctrl: [0]=candCount [1]=L
__global__ __launch_bounds__(256) void k_findbin(const unsigned* __restrict__ hist,
                                                 unsigned* __restrict__ ctrl) {
    __shared__ unsigned lh[NBIN];
    __shared__ unsigned gs[64];
    for (int i = threadIdx.x; i < NBIN; i += 256) lh[i] = hist[i];
    __syncthreads();
    int t = threadIdx.x;
    if (t < 64) {
        unsigned s = 0;
        for (int j = 0; j < 32; j++) s += lh[t * 32 + j];
        gs[t] = s;
    }
    __syncthreads();
    if (t == 0) {
        unsigned cum = 0;
        int g = 63;
        for (; g > 0; g--) { if (cum + gs[g] >= TARGET_SAMPLED) break; cum += gs[g]; }
        int b = g * 32 + 31;
        for (; b > g * 32; b--) { if (cum + lh[b] >= TARGET_SAMPLED) break; cum += lh[b]; }
        ctrl[1] = ((unsigned)b) << 21;
    }
}

// ---- full pass: copy-shaped, 4 unguarded quarter-split loads per iter ---
__global__ __launch_bounds__(256) void k_compact(const vfloat4* __restrict__ x4, long n4,
                                                 long n, const float* __restrict__ x,
                                                 unsigned* __restrict__ ctrl,
                                                 unsigned* __restrict__ candKey,
                                                 unsigned* __restrict__ candIdx,
                                                 unsigned capC) {
    const float Lf = key2f(ctrl[1]);
    const long nthreads = (long)gridDim.x * blockDim.x;
    const long gid = (long)blockIdx.x * blockDim.x + threadIdx.x;
    const long q = n4 >> 2;          // quarter (in float4 units)

#define PUSH(f, idx)                                                     \
    {                                                                    \
        unsigned p = atomicAdd(&ctrl[0], 1u);                            \
        if (p < capC) { candKey[p] = f2key(f); candIdx[p] = (idx); }     \
    }
#define PROC4(vv, base4)                                                 \
    {                                                                    \
        unsigned bb = (unsigned)((base4) * 4);                           \
        if ((vv).x >= Lf) PUSH((vv).x, bb)                               \
        if ((vv).y >= Lf) PUSH((vv).y, bb + 1)                           \
        if ((vv).z >= Lf) PUSH((vv).z, bb + 2)                           \
        if ((vv).w >= Lf) PUSH((vv).w, bb + 3)                           \
    }

    // main loop: no bounds guards — 4 independent loads in flight
    for (long i = gid; i < q; i += nthreads) {
        vfloat4 v0 = x4[i];
        vfloat4 v1 = x4[i + q];
        vfloat4 v2 = x4[i + 2 * q];
        vfloat4 v3 = x4[i + 3 * q];
        PROC4(v0, i)
        PROC4(v1, i + q)
        PROC4(v2, i + 2 * q)
        PROC4(v3, i + 3 * q)
    }

    // remainder float4s [4q, n4) — at most 3 — and scalar tail, block 0
    if (blockIdx.x == 0) {
        long rem0 = 4 * q;
        if (threadIdx.x < (int)(n4 - rem0)) {
            long i = rem0 + threadIdx.x;
            vfloat4 v = x4[i];
            PROC4(v, i)
        }
        int tail = (int)(n & 3);
        if (threadIdx.x < tail) {
            float f = x[n4 * 4 + threadIdx.x];
            if (f >= Lf) PUSH(f, (unsigned)(n4 * 4 + threadIdx.x))
        }
    }
#undef PROC4
#undef PUSH
}

// ---- fused finalize: exact T + tie-break + bucket sort + emit -----------
__global__ __launch_bounds__(1024) void k_final(const unsigned* __restrict__ candKey,
                                                const unsigned* __restrict__ candIdx,
                                                unsigned* __restrict__ ctrl, unsigned capC,
                                                unsigned* __restrict__ selKey,
                                                unsigned* __restrict__ selIdx,
                                                unsigned* __restrict__ selKeyS,
                                                unsigned* __restrict__ selIdxS,
                                                float* __restrict__ out, long n, int bshift) {
    __shared__ unsigned h[NB_BUCKET * 2];   // 32 KB
    __shared__ unsigned part[1024];
    __shared__ unsigned part2[32];
    __shared__ unsigned res[2];
    __shared__ unsigned sScalar;
    const int t = threadIdx.x;
    unsigned Nc = ctrl[0]; if (Nc > capC) Nc = capC;
    unsigned L = ctrl[1];

    // --- max key ---
    unsigned mk = 0;
    for (unsigned i = t; i < Nc; i += 1024) { unsigned k = candKey[i]; if (k > mk) mk = k; }
    part[t] = mk;
    __syncthreads();
    if (t < 32) { unsigned m = 0; for (int j = 0; j < 32; j++) { unsigned v = part[t * 32 + j]; if (v > m) m = v; } part2[t] = m; }
    __syncthreads();
    if (t == 0) { unsigned m = 0; for (int j = 0; j < 32; j++) if (part2[j] > m) m = part2[j]; sScalar = m; }
    __syncthreads();
    unsigned maxK = sScalar;

    // --- iterative radix-select: K_TOP-th from top ---
    unsigned lo = L, target = K_TOP;
    unsigned range = maxK - lo;
    int shift = 0;
    while ((range >> shift) >= NBIN) shift++;
    for (;;) {
        int nb = (int)(range >> shift) + 1;
        for (int i = t; i < nb; i += 1024) h[i] = 0;
        __syncthreads();
        for (unsigned i = t; i < Nc; i += 1024) {
            unsigned d = candKey[i] - lo;
            if (d <= range) atomicAdd(&h[d >> shift], 1u);
        }
        __syncthreads();
        int ng = (nb + 31) >> 5;
        if (t < ng) {
            unsigned s = 0; int b0 = t * 32, e = b0 + 32; if (e > nb) e = nb;
            for (int j = b0; j < e; j++) s += h[j];
            part[t] = s;
        }
        __syncthreads();
        if (t == 0) {
            unsigned cum = 0; int g = ng - 1;
            for (; g > 0; g--) { if (cum + part[g] >= target) break; cum += part[g]; }
            int hi2 = g * 32 + 31; if (hi2 > nb - 1) hi2 = nb - 1;
            int b = hi2;
            for (; b > g * 32; b--) { if (cum + h[b] >= target) break; cum += h[b]; }
            res[0] = (unsigned)b; res[1] = target - cum;
        }
        __syncthreads();
        lo += res[0] << shift; target = res[1];
        if (shift == 0) break;
        range = (1u << shift) - 1;
        shift = (shift > 11) ? shift - 11 : 0;
    }
    unsigned T = lo, R = target;

    // --- count equal keys ---
    if (t == 0) sScalar = 0;
    __syncthreads();
    for (unsigned i = t; i < Nc; i += 1024)
        if (candKey[i] == T) atomicAdd(&sScalar, 1u);
    __syncthreads();
    unsigned cntEq = sScalar;
    unsigned idxCut = 0xFFFFFFFFu;
    if (cntEq != R) {  // uniform branch
        unsigned lo2 = 0, tgt = R;
        unsigned range2 = (unsigned)(n - 1);
        int sh = 0;
        while ((range2 >> sh) >= NBIN) sh++;
        for (;;) {
            int nb = (int)(range2 >> sh) + 1;
            for (int i = t; i < nb; i += 1024) h[i] = 0;
            __syncthreads();
            for (unsigned i = t; i < Nc; i += 1024)
                if (candKey[i] == T) {
                    unsigned d = candIdx[i] - lo2;
                    if (d <= range2) atomicAdd(&h[d >> sh], 1u);
                }
            __syncthreads();
            int ng = (nb + 31) >> 5;
            if (t < ng) {
                unsigned s = 0; int b0 = t * 32, e = b0 + 32; if (e > nb) e = nb;
                for (int j = b0; j < e; j++) s += h[j];
                part[t] = s;
            }
            __syncthreads();
            if (t == 0) {
                unsigned cum = 0; int g = 0;
                for (; g < ng - 1; g++) { if (cum + part[g] >= tgt) break; cum += part[g]; }
                int b = g * 32; int hi2 = g * 32 + 31; if (hi2 > nb - 1) hi2 = nb - 1;
                for (; b < hi2; b++) { if (cum + h[b] >= tgt) break; cum += h[b]; }
                res[0] = (unsigned)b; res[1] = tgt - cum;
            }
            __syncthreads();
            lo2 += res[0] << sh; tgt = res[1];
            if (sh == 0) break;
            range2 = (1u << sh) - 1;
            sh = (sh > 11) ? sh - 11 : 0;
        }
        idxCut = lo2;
    }
    __syncthreads();

    // --- select exactly K, count buckets ---
    for (int i = t; i < NB_BUCKET; i += 1024) h[i] = 0;
    if (t == 0) sScalar = 0;
    __syncthreads();
    for (unsigned i = t; i < Nc; i += 1024) {
        unsigned k = candKey[i]; unsigned id = candIdx[i];
        if (k > T || (k == T && id <= idxCut)) {
            unsigned p = atomicAdd(&sScalar, 1u);
            if (p < K_TOP) {
                selKey[p] = k; selIdx[p] = id;
                atomicAdd(&h[id >> bshift], 1u);
            }
        }
    }
    __syncthreads();
    unsigned nSel = sScalar; if (nSel > K_TOP) nSel = K_TOP;

    // --- exclusive scan of bucket counts ---
    unsigned* bc = h;
    unsigned* bs = h + NB_BUCKET;
    { unsigned s = 0; for (int j = 0; j < 4; j++) s += bc[t * 4 + j]; part[t] = s; }
    __syncthreads();
    if (t < 32) { unsigned s = 0; for (int j = 0; j < 32; j++) s += part[t * 32 + j]; part2[t] = s; }
    __syncthreads();
    if (t == 0) { unsigned run = 0; for (int j = 0; j < 32; j++) { unsigned v = part2[j]; part2[j] = run; run += v; } }
    __syncthreads();
    if (t < 32) { unsigned run = part2[t]; for (int j = 0; j < 32; j++) { int id2 = t * 32 + j; unsigned v = part[id2]; part[id2] = run; run += v; } }
    __syncthreads();
    { unsigned run = part[t]; for (int j = 0; j < 4; j++) { bs[t * 4 + j] = run; run += bc[t * 4 + j]; } }
    __syncthreads();

    // --- scatter into bucket order (bs becomes cursor) ---
    for (unsigned g = t; g < nSel; g += 1024) {
        unsigned id = selIdx[g];
        unsigned b = id >> bshift;
        unsigned p = atomicAdd(&bs[b], 1u);
        if (p < K_TOP) { selKeyS[p] = selKey[g]; selIdxS[p] = id; }
    }
    __syncthreads();

    // --- per-bucket insertion sort by idx + emit ---
    for (int j = 0; j < 4; j++) {
        int b = t * 4 + j;
        unsigned cnt = bc[b];
        if (!cnt) continue;
        unsigned s = bs[b] - cnt;
        for (unsigned i = 0; i < cnt; i++) {
            unsigned mi = i, mv = selIdxS[s + i];
            for (unsigned q2 = i + 1; q2 < cnt; q2++) {
                unsigned v = selIdxS[s + q2];
                if (v < mv) { mv = v; mi = q2; }
            }
            if (mi != i) {
                unsigned ti = selIdxS[s + i]; selIdxS[s + i] = selIdxS[s + mi]; selIdxS[s + mi] = ti;
                unsigned tk = selKeyS[s + i]; selKeyS[s + i] = selKeyS[s + mi]; selKeyS[s + mi] = tk;
            }
            out[s + i] = key2f(selKeyS[s + i]);
        }
    }
}

// ---- host launch --------------------------------------------------------
// ws words: hist[0..2047], ctrl[2048..2055], selKey[2056..7055], selIdx[7056..12055],
//           selKeyS[12056..17055], selIdxS[17056..22055], cand arrays from 24576.
extern "C" void kernel_launch(void* const* d_in, const int* in_sizes, int n_in,
                              void* d_out, int out_size, void* d_ws, size_t ws_size,
                              hipStream_t stream) {
    const float* x = (const float*)d_in[0];
    long n = in_sizes[0];
    float* out = (float*)d_out;
    unsigned* w = (unsigned*)d_ws;

    unsigned* hist    = w;
    unsigned* ctrl    = w + 2048;
    unsigned* selKey  = w + 2056;
    unsigned* selIdx  = w + 7056;
    unsigned* selKeyS = w + 12056;
    unsigned* selIdxS = w + 17056;
    const size_t CAND_BASE = 24576;
    size_t words = ws_size / 4;
    unsigned capC = 0;
    if (words > CAND_BASE + 64) {
        size_t c = (words - CAND_BASE) / 2;
        if (c > (size_t)(4u << 20)) c = (size_t)(4u << 20);
        capC = (unsigned)c;
    }
    unsigned* candKey = w + CAND_BASE;
    unsigned* candIdx = candKey + capC;

    int bshift = 0;
    while (((n - 1) >> bshift) >= NB_BUCKET) bshift++;

    (void)hipMemsetAsync(d_ws, 0, 2056u * 4u + 32u, stream);

    long n4 = n / 4;
    k_sample<<<256, 256, 0, stream>>>((const float4*)x, n4, hist);
    k_findbin<<<1, 256, 0, stream>>>(hist, ctrl);
    k_compact<<<4096, 256, 0, stream>>>((const vfloat4*)x, n4, n, x, ctrl,
                                        candKey, candIdx, capC);
    k_final<<<1, 1024, 0, stream>>>(candKey, candIdx, ctrl, capC,
                                    selKey, selIdx, selKeyS, selIdxS, out, n, bshift);
}